// Round 4
// baseline (19515.620 us; speedup 1.0000x reference)
//
#include <hip/hip_runtime.h>
#include <hip/hip_bf16.h>
#include <cstdint>
#include <cstddef>

typedef unsigned short u16;
typedef unsigned long long u64;
typedef __attribute__((ext_vector_type(8))) short short8;
typedef __attribute__((ext_vector_type(4))) float f32x4;

// ---------------- constants ----------------
#define NB 32          // batch
#define NT 1024        // time steps
#define NH 1024        // hidden
#define TCH 128        // time chunk
#define NCH 8          // number of chunks

// workspace offsets (bytes); total ~177 MB
#define O_XB   0ull                 // x bf16: 64MB
#define O_WIH  67108864ull          // wih bf16 both dirs: 16MB
#define O_WHHP 83886080ull          // whh packed hi/lo frag-linear: 32MB
#define O_BIAS 117440512ull         // bias sums f32: 32KB
#define O_HBUF 117473280ull         // h ping-pong bf16 [dir][buf][b][j]: 256KB
#define O_CST  117735424ull         // c state f32 [dir][b][j]: 256KB
#define O_CNT  117997568ull         // barrier counters: 4KB
#define O_GX   118001664ull         // Gx bf16 chunk [dir][tl][b][npr]: 64MB

__device__ __forceinline__ u16 f2bf(float f){
  union { float f; unsigned u; } v; v.f = f;
  unsigned r = v.u + 0x7FFFu + ((v.u >> 16) & 1u);
  return (u16)(r >> 16);
}
__device__ __forceinline__ float bf2f(u16 h){
  union { unsigned u; float f; } v; v.u = ((unsigned)h) << 16;
  return v.f;
}
__device__ __forceinline__ float sig_f(float x){ return 1.0f / (1.0f + __expf(-x)); }
__device__ __forceinline__ float tanh_f(float x){ return 1.0f - 2.0f / (1.0f + __expf(2.0f * x)); }

__device__ __forceinline__ void g2l16(const void* g, void* l){
  __builtin_amdgcn_global_load_lds(
      (const __attribute__((address_space(1))) unsigned int*)g,
      (__attribute__((address_space(3))) unsigned int*)l, 16, 0, 0);
}

__device__ __forceinline__ float sel4(float s0, float s1, float s2, float s3, int k){
  float a = (k & 1) ? s1 : s0;
  float b = (k & 1) ? s3 : s2;
  return (k & 2) ? b : a;
}

// ---------------- f32 -> bf16 convert ----------------
__global__ void k_cvt(const float* __restrict__ src, u16* __restrict__ dst, int n){
  int i = (blockIdx.x * blockDim.x + threadIdx.x) * 4;
  int stride = gridDim.x * blockDim.x * 4;
  for (; i < n; i += stride){
    float4 v = *(const float4*)(src + i);
    uint2 p;
    p.x = (unsigned)f2bf(v.x) | ((unsigned)f2bf(v.y) << 16);
    p.y = (unsigned)f2bf(v.z) | ((unsigned)f2bf(v.w) << 16);
    *(uint2*)(dst + i) = p;
  }
}

// ---------------- pack Whh into hi/lo fragment-linear layout ----------------
// frag index = ((dir*256 + ug)*32 + ks)*2 + part ; 1024B per frag (lane*16B)
// lane c=lane&15 -> weight row n = (c>>2)*1024 + ug*4 + (c&3); k-chunk (lane>>4)*8
__global__ void k_pack_whh(const float* __restrict__ whh_f, const float* __restrict__ whh_r,
                           u16* __restrict__ dst){
  int bx = blockIdx.x;              // 512 blocks: dir*256 + ug
  int dir = bx >> 8, ug = bx & 255;
  const float* whh = dir ? whh_r : whh_f;
  int tid = threadIdx.x;
  int lane = tid & 63, wq = tid >> 6;
  int c = lane & 15;
  int n = (c >> 2) * 1024 + ug * 4 + (c & 3);
  int kkb = (lane >> 4) * 8;
  size_t fb = ((size_t)(dir * 256 + ug) * 32) * 2;
  for (int q = 0; q < 8; q++){
    int ks = wq * 8 + q;
    const float4* p = (const float4*)(whh + (size_t)n * 1024 + ks * 32 + kkb);
    float4 w0 = p[0], w1 = p[1];
    float w[8] = {w0.x, w0.y, w0.z, w0.w, w1.x, w1.y, w1.z, w1.w};
    unsigned hh[4], ll[4];
    #pragma unroll
    for (int e = 0; e < 4; e++){
      u16 h0 = f2bf(w[2*e]),   l0 = f2bf(w[2*e]   - bf2f(f2bf(w[2*e])));
      u16 h1 = f2bf(w[2*e+1]), l1 = f2bf(w[2*e+1] - bf2f(f2bf(w[2*e+1])));
      hh[e] = (unsigned)h0 | ((unsigned)h1 << 16);
      ll[e] = (unsigned)l0 | ((unsigned)l1 << 16);
    }
    uint4* dh = (uint4*)(dst + (fb + (size_t)ks * 2 + 0) * 512 + lane * 8);
    uint4* dl = (uint4*)(dst + (fb + (size_t)ks * 2 + 1) * 512 + lane * 8);
    *dh = make_uint4(hh[0], hh[1], hh[2], hh[3]);
    *dl = make_uint4(ll[0], ll[1], ll[2], ll[3]);
  }
}

// ---------------- init: bias sums, h0->bf16, c state, zero counters ----------------
__global__ void k_init(const float* __restrict__ h0, const float* __restrict__ c0,
                       const float* __restrict__ bih_f, const float* __restrict__ bhh_f,
                       const float* __restrict__ bih_r, const float* __restrict__ bhh_r,
                       u16* __restrict__ hbuf, float* __restrict__ cst,
                       float* __restrict__ bias, int* __restrict__ cnt){
  int i = blockIdx.x * blockDim.x + threadIdx.x;
  int stride = gridDim.x * blockDim.x;
  for (int k = i; k < 32768; k += stride){
    u16 v = f2bf(h0[k]);
    hbuf[k] = v;            // dir0 buf0
    hbuf[65536 + k] = v;    // dir1 buf0
    float cv = c0[k];
    cst[k] = cv;            // dir0
    cst[32768 + k] = cv;    // dir1
  }
  for (int k = i; k < 8192; k += stride){
    if (k < 4096) bias[k] = bih_f[k] + bhh_f[k];
    else          bias[k] = bih_r[k - 4096] + bhh_r[k - 4096];
  }
  for (int k = i; k < 1024; k += stride) cnt[k] = 0;
}

// ---------------- Phase 1: Gx chunk = x @ Wih^T + bias, store bf16 permuted ----------------
// grid (32, 32, 2): n0 = bx*128 (gate cols), by = batch, bz = dir. 128x128 tile, BK=64.
__global__ __launch_bounds__(256, 2) void k_gemm(const u16* __restrict__ xb,
                                                 const u16* __restrict__ wih,
                                                 const float* __restrict__ bias,
                                                 u16* __restrict__ gx, int chunk){
  __shared__ u16 smem[2 * 16384]; // 2 x 32KB frag-linear, frag f at f*512 u16; A:0..15 B:16..31
  const int tid = threadIdx.x;
  const int lane = tid & 63, wid = tid >> 6;
  const int mi = wid >> 1, ni = wid & 1;
  const int c = lane & 15, rg = lane >> 4;
  const int n0 = blockIdx.x * 128;
  const int bb = blockIdx.y;              // batch
  const int dir = blockIdx.z;
  const u16* wd = wih + (size_t)dir * 4194304;

  f32x4 acc[4][4] = {};

  auto stage = [&](int buf, int k0){
    #pragma unroll
    for (int q = 0; q < 8; q++){
      int f = wid * 8 + q;
      int ks = f & 1;
      int kk = k0 + ks * 32 + rg * 8;
      const u16* src;
      if (f < 16){
        int lr = (f >> 1) * 16 + c;       // local t within chunk
        int tg = dir ? (1023 - chunk * TCH - lr) : (chunk * TCH + lr);
        src = xb + (size_t)(bb * 1024 + tg) * 1024 + kk;
      } else {
        int nt = (f - 16) >> 1;
        src = wd + (size_t)(n0 + nt * 16 + c) * 1024 + kk;
      }
      g2l16((const void*)src, (void*)(smem + buf * 16384 + f * 512));
    }
  };

  stage(0, 0);
  asm volatile("s_waitcnt vmcnt(0)" ::: "memory");
  __syncthreads();

  for (int it = 0; it < 16; it++){
    int cur = it & 1;
    if (it < 15) stage(cur ^ 1, (it + 1) * 64);
    const u16* bp = smem + cur * 16384;
    #pragma unroll
    for (int ks = 0; ks < 2; ks++){
      short8 a[4], b[4];
      #pragma unroll
      for (int im = 0; im < 4; im++)
        a[im] = *(const short8*)(bp + ((mi * 4 + im) * 2 + ks) * 512 + lane * 8);
      #pragma unroll
      for (int in_ = 0; in_ < 4; in_++)
        b[in_] = *(const short8*)(bp + 8192 + ((ni * 4 + in_) * 2 + ks) * 512 + lane * 8);
      #pragma unroll
      for (int im = 0; im < 4; im++)
        #pragma unroll
        for (int in_ = 0; in_ < 4; in_++)
          acc[im][in_] = __builtin_amdgcn_mfma_f32_16x16x32_bf16(a[im], b[in_], acc[im][in_], 0, 0, 0);
    }
    asm volatile("s_waitcnt vmcnt(0)" ::: "memory");
    __syncthreads();
  }

  // epilogue: add bias, permute col, store bf16 at gx[dir][tl][b][npr]
  u16* gxd = gx + (size_t)dir * (TCH * 32 * 4096);
  const float* bd = bias + dir * 4096;
  #pragma unroll
  for (int in_ = 0; in_ < 4; in_++){
    int nn = n0 + (ni * 4 + in_) * 16 + c;
    float bv = bd[nn];
    int npr = ((nn & 1023) >> 3) * 32 + ((nn >> 10) << 3) + (nn & 7);
    #pragma unroll
    for (int im = 0; im < 4; im++){
      #pragma unroll
      for (int r = 0; r < 4; r++){
        int tl = (mi * 4 + im) * 16 + rg * 4 + r;   // local t
        gxd[(size_t)(tl * 32 + bb) * 4096 + npr] = f2bf(acc[im][in_][r] + bv);
      }
    }
  }
}

// ---------------- Phase 2: recurrent kernel, one chunk of TCH steps ----------------
// 64 blocks x 512 threads (8 waves). dir = bx>>5, 32 blocks/dir, 32 hidden units/block.
// Wave uq handles 4 units (16 gate-cols) x all 32 batch rows (2 M-tiles).
// B (Whh hi/lo) streamed from L2 (512KB/block x 8 blocks/XCD = 4MB, L2-resident).
// h broadcast: relaxed agent u64 atomics via LLC; per-direction 2-line barrier.
__global__ __launch_bounds__(512, 1) void k_rnn(const u16* __restrict__ gx,
                                                const u16* __restrict__ whhp,
                                                u16* __restrict__ hbuf,
                                                float* __restrict__ cstate,
                                                float* __restrict__ dout,
                                                int* __restrict__ cnt,
                                                int s0, int bar0){
  __shared__ char smem[65536]; // h tile: row r at r*2048, byte b at b ^ (((r&7)^((b>>8)&7))<<4)
  __shared__ u16 tb2[32][32];  // h_new transpose buffer [row][unit-in-block]
  const int tid = threadIdx.x;
  const int lane = tid & 63, uq = tid >> 6;     // wave id 0..7
  const int bx = blockIdx.x;
  const int dir = bx >> 5, ub = bx & 31;
  const int u0 = ub * 32;
  const int c = lane & 15, rg = lane >> 4;
  const int g = c >> 2, jj = c & 3;
  const int j = u0 + uq * 4 + jj;
  const int ug = ub * 8 + uq;

  // --- c state: 2 M-tiles x 4 rows for this lane's hidden j ---
  float cst[2][4];
  #pragma unroll
  for (int mi = 0; mi < 2; mi++)
    #pragma unroll
    for (int r = 0; r < 4; r++)
      cst[mi][r] = cstate[(size_t)dir * 32768 + (size_t)(mi * 16 + rg * 4 + r) * 1024 + j];

  const size_t fbase = ((size_t)(dir * 256 + ug) * 32) * 2;  // B frag index base
  // gx permuted column for (g, j)
  const int npr = (ub * 4 + (uq >> 1)) * 32 + g * 8 + (uq & 1) * 4 + jj;

  int* arr = cnt + dir * 64;        // arrival counter (own cacheline)
  int* rel = cnt + 128 + dir * 64;  // release word   (own cacheline)

  // gx prefetch for t=0
  u16 gxu[2][4];
  {
    const size_t gof = (size_t)dir * (TCH * 32 * 4096) + npr;
    #pragma unroll
    for (int mi = 0; mi < 2; mi++)
      #pragma unroll
      for (int r = 0; r < 4; r++)
        gxu[mi][r] = gx[gof + (size_t)(mi * 16 + rg * 4 + r) * 4096];
  }

  for (int t = 0; t < TCH; t++){
    const int s = s0 + t;
    const u16* hcur = hbuf + ((size_t)((dir << 1) + (s & 1))) * 32768;
    u16* hnxt = hbuf + ((size_t)((dir << 1) + ((s + 1) & 1))) * 32768;

    // stage h -> LDS: 16 x u64 relaxed agent loads per thread (coalesced), swizzled writes
    {
      const u64* hc = (const u64*)hcur;
      #pragma unroll
      for (int i = 0; i < 16; i++){
        int flat = i * 512 + tid;
        u64 v = __hip_atomic_load((u64*)(uintptr_t)(hc + flat),
                                  __ATOMIC_RELAXED, __HIP_MEMORY_SCOPE_AGENT);
        int row = flat >> 8, bo = (flat & 255) * 8;
        int swz = (((row & 7) ^ ((bo >> 8) & 7)) << 4);
        *(u64*)(smem + row * 2048 + (bo ^ swz)) = v;
      }
    }
    __syncthreads();

    // gates = h @ Whh^T, 2 M-tiles x (hi+lo): 4 independent MFMA chains
    f32x4 a0h = {0.f,0.f,0.f,0.f}, a0l = {0.f,0.f,0.f,0.f};
    f32x4 a1h = {0.f,0.f,0.f,0.f}, a1l = {0.f,0.f,0.f,0.f};
    const int r0base = c * 2048;
    const int r1base = (16 + c) * 2048;
    #pragma unroll
    for (int ks = 0; ks < 32; ks++){
      const u16* wp = whhp + (fbase + ks * 2) * 512 + lane * 8;
      short8 bh = *(const short8*)(wp);
      short8 bl = *(const short8*)(wp + 512);
      int b = ks * 64 + rg * 16;
      int swz = (((c & 7) ^ ((b >> 8) & 7)) << 4);   // (16+c)&7 == c&7
      short8 a0 = *(const short8*)(smem + r0base + (b ^ swz));
      short8 a1 = *(const short8*)(smem + r1base + (b ^ swz));
      a0h = __builtin_amdgcn_mfma_f32_16x16x32_bf16(a0, bh, a0h, 0, 0, 0);
      a0l = __builtin_amdgcn_mfma_f32_16x16x32_bf16(a0, bl, a0l, 0, 0, 0);
      a1h = __builtin_amdgcn_mfma_f32_16x16x32_bf16(a1, bh, a1h, 0, 0, 0);
      a1l = __builtin_amdgcn_mfma_f32_16x16x32_bf16(a1, bl, a1l, 0, 0, 0);
    }

    // elementwise LSTM cell (gate exchange via ds_swizzle xor 4/8/12)
    #pragma unroll
    for (int mi = 0; mi < 2; mi++){
      #pragma unroll
      for (int r = 0; r < 4; r++){
        float ahv = mi ? a1h[r] : a0h[r];
        float alv = mi ? a1l[r] : a0l[r];
        float v = (ahv + alv) + bf2f(gxu[mi][r]);
        float act = (g == 2) ? tanh_f(v) : sig_f(v);
        float a4  = __int_as_float(__builtin_amdgcn_ds_swizzle(__float_as_int(act), 0x101F));
        float a8  = __int_as_float(__builtin_amdgcn_ds_swizzle(__float_as_int(act), 0x201F));
        float a12 = __int_as_float(__builtin_amdgcn_ds_swizzle(__float_as_int(act), 0x301F));
        float i_s = sel4(act, a4, a8, a12, g);
        float f_s = sel4(act, a4, a8, a12, g ^ 1);
        float g_t = sel4(act, a4, a8, a12, g ^ 2);
        float o_s = sel4(act, a4, a8, a12, g ^ 3);
        float cn = f_s * cst[mi][r] + i_s * g_t;
        cst[mi][r] = cn;
        float hn = o_s * tanh_f(cn);
        if (g == 0){
          int brow = mi * 16 + rg * 4 + r;
          tb2[brow][uq * 4 + jj] = f2bf(hn);
          if (s == 1023)
            dout[(size_t)dir * 32768 + (size_t)brow * 1024 + j] = hn;
          if (t == TCH - 1)
            cstate[(size_t)dir * 32768 + (size_t)brow * 1024 + j] = cn;
        }
      }
    }
    __syncthreads();   // tb2 complete; also guards smem h-tile reuse

    // h_new stores: 256 threads, u64 relaxed agent stores (write-through to LLC)
    if (tid < 256){
      int row = tid >> 3, seg = tid & 7;
      u64 v = *(const u64*)&tb2[row][seg * 4];
      __hip_atomic_store((u64*)(hnxt + (size_t)row * 1024 + u0 + seg * 4), v,
                         __ATOMIC_RELAXED, __HIP_MEMORY_SCOPE_AGENT);
    }

    if (t < TCH - 1){
      // prefetch next step's gx while stores drain
      const size_t gof = (size_t)dir * (TCH * 32 * 4096) + (size_t)(t + 1) * 131072 + npr;
      #pragma unroll
      for (int mi = 0; mi < 2; mi++)
        #pragma unroll
        for (int r = 0; r < 4; r++)
          gxu[mi][r] = gx[gof + (size_t)(mi * 16 + rg * 4 + r) * 4096];

      asm volatile("s_waitcnt vmcnt(0)" ::: "memory");  // every wave drains its own stores
      __syncthreads();
      if (tid == 0){
        const int bar = bar0 + t;
        int old = __hip_atomic_fetch_add(arr, 1, __ATOMIC_RELAXED, __HIP_MEMORY_SCOPE_AGENT);
        if (old == 32 * (bar + 1) - 1){
          __hip_atomic_store(rel, bar + 1, __ATOMIC_RELAXED, __HIP_MEMORY_SCOPE_AGENT);
        } else {
          while (__hip_atomic_load(rel, __ATOMIC_RELAXED, __HIP_MEMORY_SCOPE_AGENT) < bar + 1)
            __builtin_amdgcn_s_sleep(2);
        }
      }
      __syncthreads();
    }
  }
}

// ---------------- host launcher ----------------
extern "C" void kernel_launch(void* const* d_in, const int* in_sizes, int n_in,
                              void* d_out, int out_size, void* d_ws, size_t ws_size,
                              hipStream_t stream){
  const float* x     = (const float*)d_in[0];
  const float* h0    = (const float*)d_in[1];
  const float* c0    = (const float*)d_in[2];
  const float* Wih_f = (const float*)d_in[3];
  const float* Whh_f = (const float*)d_in[4];
  const float* bih_f = (const float*)d_in[5];
  const float* bhh_f = (const float*)d_in[6];
  const float* Wih_r = (const float*)d_in[7];
  const float* Whh_r = (const float*)d_in[8];
  const float* bih_r = (const float*)d_in[9];
  const float* bhh_r = (const float*)d_in[10];
  float* out = (float*)d_out;

  char* ws = (char*)d_ws;
  u16*   xb    = (u16*)(ws + O_XB);
  u16*   wih   = (u16*)(ws + O_WIH);
  u16*   whhp  = (u16*)(ws + O_WHHP);
  float* bias  = (float*)(ws + O_BIAS);
  u16*   hbuf  = (u16*)(ws + O_HBUF);
  float* cstw  = (float*)(ws + O_CST);
  int*   cnt   = (int*)(ws + O_CNT);
  u16*   gx    = (u16*)(ws + O_GX);

  // conversions / packing / init (independent)
  k_cvt<<<2048, 256, 0, stream>>>(x, xb, 32 * 1024 * 1024);
  k_cvt<<<512, 256, 0, stream>>>(Wih_f, wih, 4096 * 1024);
  k_cvt<<<512, 256, 0, stream>>>(Wih_r, wih + 4194304, 4096 * 1024);
  k_pack_whh<<<512, 256, 0, stream>>>(Whh_f, Whh_r, whhp);
  k_init<<<64, 256, 0, stream>>>(h0, c0, bih_f, bhh_f, bih_r, bhh_r, hbuf, cstw, bias, cnt);

  // chunked: input-projection GEMM then TCH recurrent steps, 8x
  for (int ch = 0; ch < NCH; ch++){
    k_gemm<<<dim3(32, 32, 2), 256, 0, stream>>>(xb, wih, bias, gx, ch);
    k_rnn<<<dim3(64), dim3(512), 0, stream>>>(gx, whhp, hbuf, cstw, out, cnt,
                                              ch * TCH, ch * (TCH - 1));
  }
}

// Round 5
// 7549.850 us; speedup vs baseline: 2.5849x; 2.5849x over previous
//
#include <hip/hip_runtime.h>
#include <hip/hip_bf16.h>
#include <cstdint>
#include <cstddef>

typedef unsigned short u16;
typedef unsigned long long u64;
typedef __attribute__((ext_vector_type(8))) short short8;
typedef __attribute__((ext_vector_type(4))) float f32x4;
typedef __attribute__((ext_vector_type(4))) unsigned u32x4;

// ---------------- constants ----------------
#define NB 32          // batch
#define NT 1024        // time steps
#define NH 1024        // hidden
#define TCH 128        // time chunk
#define NCH 8          // number of chunks

// workspace offsets (bytes); total ~177 MB
#define O_XB   0ull                 // x bf16: 64MB
#define O_WIH  67108864ull          // wih bf16 both dirs: 16MB
#define O_WHHP 83886080ull          // whh packed hi/lo frag-linear: 32MB
#define O_BIAS 117440512ull         // bias sums f32: 32KB
#define O_HBUF 117473280ull         // h images: 4 groups x 2 bufs x 32KB = 256KB
#define O_CST  117735424ull         // c state f32 [dir][b][j]: 256KB
#define O_CNT  117997568ull         // flags: 4 groups x 64 ints (+slack): 4KB
#define O_GX   118001664ull         // Gx bf16 chunk [dir][tl][b][npr]: 64MB

__device__ __forceinline__ u16 f2bf(float f){
  union { float f; unsigned u; } v; v.f = f;
  unsigned r = v.u + 0x7FFFu + ((v.u >> 16) & 1u);
  return (u16)(r >> 16);
}
__device__ __forceinline__ float bf2f(u16 h){
  union { unsigned u; float f; } v; v.u = ((unsigned)h) << 16;
  return v.f;
}
__device__ __forceinline__ float sig_f(float x){ return 1.0f / (1.0f + __expf(-x)); }
__device__ __forceinline__ float tanh_f(float x){ return 1.0f - 2.0f / (1.0f + __expf(2.0f * x)); }

// plain global->LDS DMA (L2-cached) — used by k_gemm
__device__ __forceinline__ void g2l16(const void* g, void* l){
  __builtin_amdgcn_global_load_lds(
      (const __attribute__((address_space(1))) unsigned int*)g,
      (__attribute__((address_space(3))) unsigned int*)l, 16, 0, 0);
}
// coherent global->LDS DMA: aux = SC0|SC1 = 17 -> bypass L0+L2, read at LLC
__device__ __forceinline__ void g2l16c(const void* g, void* l){
  __builtin_amdgcn_global_load_lds(
      (const __attribute__((address_space(1))) unsigned int*)g,
      (__attribute__((address_space(3))) unsigned int*)l, 16, 0, 17);
}
// coherent 16B store (write-through to LLC)
__device__ __forceinline__ void store16_llc(void* p, u32x4 v){
  asm volatile("global_store_dwordx4 %0, %1, off sc0 sc1"
               :: "v"((unsigned long long)(uintptr_t)p), "v"(v) : "memory");
}

__device__ __forceinline__ float sel4(float s0, float s1, float s2, float s3, int k){
  float a = (k & 1) ? s1 : s0;
  float b = (k & 1) ? s3 : s2;
  return (k & 2) ? b : a;
}

// image byte offset for (row lr in 0..15, pre-swizzle byte bo in 0..2047)
__device__ __forceinline__ int img_off(int lr, int bo){
  return lr * 2048 + (bo ^ ((((lr & 7) ^ ((bo >> 8) & 7))) << 4));
}

// ---------------- f32 -> bf16 convert ----------------
__global__ void k_cvt(const float* __restrict__ src, u16* __restrict__ dst, int n){
  int i = (blockIdx.x * blockDim.x + threadIdx.x) * 4;
  int stride = gridDim.x * blockDim.x * 4;
  for (; i < n; i += stride){
    float4 v = *(const float4*)(src + i);
    uint2 p;
    p.x = (unsigned)f2bf(v.x) | ((unsigned)f2bf(v.y) << 16);
    p.y = (unsigned)f2bf(v.z) | ((unsigned)f2bf(v.w) << 16);
    *(uint2*)(dst + i) = p;
  }
}

// ---------------- pack Whh into hi/lo fragment-linear layout (round-3 layout) ----
// frag index = (((dir*128 + jg)*2 + ni)*32 + ks)*2 + part ; 1024B per frag (lane*16B)
// lane c=lane&15 -> weight row n = (c>>2)*1024 + jg*8 + ni*4 + (c&3); k-chunk (lane>>4)*8
__global__ void k_pack_whh(const float* __restrict__ whh_f, const float* __restrict__ whh_r,
                           u16* __restrict__ dst){
  int bx = blockIdx.x;              // 512 blocks: dir*256 + jg*2 + ni
  int dir = bx >> 8, rem = bx & 255;
  int jg = rem >> 1, ni = rem & 1;
  const float* whh = dir ? whh_r : whh_f;
  int tid = threadIdx.x;
  int lane = tid & 63, wq = tid >> 6;
  int c = lane & 15;
  int n = (c >> 2) * 1024 + jg * 8 + ni * 4 + (c & 3);
  int kkb = (lane >> 4) * 8;
  size_t fb = ((((size_t)dir * 128 + jg) * 2 + ni) * 32) * 2;
  for (int q = 0; q < 8; q++){
    int ks = wq * 8 + q;
    const float4* p = (const float4*)(whh + (size_t)n * 1024 + ks * 32 + kkb);
    float4 w0 = p[0], w1 = p[1];
    float w[8] = {w0.x, w0.y, w0.z, w0.w, w1.x, w1.y, w1.z, w1.w};
    unsigned hh[4], ll[4];
    #pragma unroll
    for (int e = 0; e < 4; e++){
      u16 h0 = f2bf(w[2*e]),   l0 = f2bf(w[2*e]   - bf2f(f2bf(w[2*e])));
      u16 h1 = f2bf(w[2*e+1]), l1 = f2bf(w[2*e+1] - bf2f(f2bf(w[2*e+1])));
      hh[e] = (unsigned)h0 | ((unsigned)h1 << 16);
      ll[e] = (unsigned)l0 | ((unsigned)l1 << 16);
    }
    uint4* dh = (uint4*)(dst + (fb + (size_t)ks * 2 + 0) * 512 + lane * 8);
    uint4* dl = (uint4*)(dst + (fb + (size_t)ks * 2 + 1) * 512 + lane * 8);
    *dh = make_uint4(hh[0], hh[1], hh[2], hh[3]);
    *dl = make_uint4(ll[0], ll[1], ll[2], ll[3]);
  }
}

// ---------------- init: bias sums, h0 -> swizzled images, c state, zero flags ----
__global__ void k_init(const float* __restrict__ h0, const float* __restrict__ c0,
                       const float* __restrict__ bih_f, const float* __restrict__ bhh_f,
                       const float* __restrict__ bih_r, const float* __restrict__ bhh_r,
                       char* __restrict__ hbuf, float* __restrict__ cst,
                       float* __restrict__ bias, int* __restrict__ cnt){
  int i = blockIdx.x * blockDim.x + threadIdx.x;
  int stride = gridDim.x * blockDim.x;
  for (int k = i; k < 32768; k += stride){
    int b = k >> 10, j = k & 1023;
    int lr = b & 15, mhb = b >> 4;
    u16 v = f2bf(h0[k]);
    int off = img_off(lr, 2 * j);
    // group = dir*2 + mh; image base = (group*2 + parity0)*32768
    *(u16*)(hbuf + (size_t)((0 * 2 + mhb) * 2) * 32768 + off) = v;  // dir 0
    *(u16*)(hbuf + (size_t)((1 * 2 + mhb) * 2) * 32768 + off) = v;  // dir 1
    float cv = c0[k];
    cst[k] = cv;            // dir0
    cst[32768 + k] = cv;    // dir1
  }
  for (int k = i; k < 8192; k += stride){
    if (k < 4096) bias[k] = bih_f[k] + bhh_f[k];
    else          bias[k] = bih_r[k - 4096] + bhh_r[k - 4096];
  }
  for (int k = i; k < 1024; k += stride) cnt[k] = 0;
}

// ---------------- Phase 1: Gx chunk = x @ Wih^T + bias, store bf16 permuted ----------------
// grid (32, 32, 2): n0 = bx*128 (gate cols), by = batch, bz = dir. 128x128 tile, BK=64.
__global__ __launch_bounds__(256, 2) void k_gemm(const u16* __restrict__ xb,
                                                 const u16* __restrict__ wih,
                                                 const float* __restrict__ bias,
                                                 u16* __restrict__ gx, int chunk){
  __shared__ u16 smem[2 * 16384]; // 2 x 32KB frag-linear, frag f at f*512 u16; A:0..15 B:16..31
  const int tid = threadIdx.x;
  const int lane = tid & 63, wid = tid >> 6;
  const int mi = wid >> 1, ni = wid & 1;
  const int c = lane & 15, rg = lane >> 4;
  const int n0 = blockIdx.x * 128;
  const int bb = blockIdx.y;              // batch
  const int dir = blockIdx.z;
  const u16* wd = wih + (size_t)dir * 4194304;

  f32x4 acc[4][4] = {};

  auto stage = [&](int buf, int k0){
    #pragma unroll
    for (int q = 0; q < 8; q++){
      int f = wid * 8 + q;
      int ks = f & 1;
      int kk = k0 + ks * 32 + rg * 8;
      const u16* src;
      if (f < 16){
        int lr = (f >> 1) * 16 + c;       // local t within chunk
        int tg = dir ? (1023 - chunk * TCH - lr) : (chunk * TCH + lr);
        src = xb + (size_t)(bb * 1024 + tg) * 1024 + kk;
      } else {
        int nt = (f - 16) >> 1;
        src = wd + (size_t)(n0 + nt * 16 + c) * 1024 + kk;
      }
      g2l16((const void*)src, (void*)(smem + buf * 16384 + f * 512));
    }
  };

  stage(0, 0);
  asm volatile("s_waitcnt vmcnt(0)" ::: "memory");
  __syncthreads();

  for (int it = 0; it < 16; it++){
    int cur = it & 1;
    if (it < 15) stage(cur ^ 1, (it + 1) * 64);
    const u16* bp = smem + cur * 16384;
    #pragma unroll
    for (int ks = 0; ks < 2; ks++){
      short8 a[4], b[4];
      #pragma unroll
      for (int im = 0; im < 4; im++)
        a[im] = *(const short8*)(bp + ((mi * 4 + im) * 2 + ks) * 512 + lane * 8);
      #pragma unroll
      for (int in_ = 0; in_ < 4; in_++)
        b[in_] = *(const short8*)(bp + 8192 + ((ni * 4 + in_) * 2 + ks) * 512 + lane * 8);
      #pragma unroll
      for (int im = 0; im < 4; im++)
        #pragma unroll
        for (int in_ = 0; in_ < 4; in_++)
          acc[im][in_] = __builtin_amdgcn_mfma_f32_16x16x32_bf16(a[im], b[in_], acc[im][in_], 0, 0, 0);
    }
    asm volatile("s_waitcnt vmcnt(0)" ::: "memory");
    __syncthreads();
  }

  // epilogue: add bias, permute col, store bf16 at gx[dir][tl][b][npr]
  u16* gxd = gx + (size_t)dir * (TCH * 32 * 4096);
  const float* bd = bias + dir * 4096;
  #pragma unroll
  for (int in_ = 0; in_ < 4; in_++){
    int nn = n0 + (ni * 4 + in_) * 16 + c;
    float bv = bd[nn];
    int npr = ((nn & 1023) >> 3) * 32 + ((nn >> 10) << 3) + (nn & 7);
    #pragma unroll
    for (int im = 0; im < 4; im++){
      #pragma unroll
      for (int r = 0; r < 4; r++){
        int tl = (mi * 4 + im) * 16 + rg * 4 + r;   // local t
        gxd[(size_t)(tl * 32 + bb) * 4096 + npr] = f2bf(acc[im][in_][r] + bv);
      }
    }
  }
}

// ---------------- Phase 2: recurrent kernel, one chunk of TCH steps ----------------
// 256 blocks x 256 thr (4 waves), 1 block/CU. bx: dir = bx>>7; mh = (bx>>6)&1 (16-batch
// half); ug = bx&63 (16 hidden units). 4 independent groups (dir,mh) of 64 blocks.
// Weights AGPR/VGPR-resident (hi+lo). h kept as pre-swizzled 32KB LDS image in hbuf;
// staged via global_load_lds aux=SC0|SC1 (bypass stale L0/L2, read LLC). Producers
// write swizzled 16B stores sc0 sc1. Barrier = per-block monotonic flag stores +
// parallel flag polling (no atomic RMW chains).
__global__ __launch_bounds__(256, 1) void k_rnn(const u16* __restrict__ gx,
                                                const u16* __restrict__ whhp,
                                                char* __restrict__ hbuf,
                                                float* __restrict__ cstate,
                                                float* __restrict__ dout,
                                                int* __restrict__ cnt,
                                                int s0, int bar0){
  __shared__ char smem[32768];                 // h image for (dir,mh): 16 rows x 2048B
  __shared__ __align__(16) u16 tb[16][16];     // h_new transpose buffer [row][unit]
  const int tid = threadIdx.x;
  const int lane = tid & 63, wid = tid >> 6;
  const int bx = blockIdx.x;
  const int dir = bx >> 7, mh = (bx >> 6) & 1, ug = bx & 63;
  const int grp = dir * 2 + mh;
  const int c = lane & 15, rg = lane >> 4;
  const int g = c >> 2, jj = c & 3;
  const int u = ug * 16 + wid * 4 + jj;        // hidden unit for this lane's column
  const int jg = ug * 2 + (wid >> 1), ni = wid & 1;

  // --- Whh fragments into registers (hi + lo) ---
  short8 Bhi[32], Blo[32];
  {
    size_t fb = ((((size_t)dir * 128 + jg) * 2 + ni) * 32) * 2;
    #pragma unroll
    for (int ks = 0; ks < 32; ks++){
      Bhi[ks] = *(const short8*)(whhp + (fb + ks * 2 + 0) * 512 + lane * 8);
      Blo[ks] = *(const short8*)(whhp + (fb + ks * 2 + 1) * 512 + lane * 8);
    }
  }

  // --- c state: rows B = mh*16 + rg*4 + r ---
  float cst[4];
  #pragma unroll
  for (int r = 0; r < 4; r++)
    cst[r] = cstate[(size_t)dir * 32768 + (size_t)(mh * 16 + rg * 4 + r) * 1024 + u];

  const int npr = (u >> 3) * 32 + g * 8 + (u & 7);
  int* flags = cnt + grp * 64;

  // gx prefetch for t=0
  u16 gxu[4];
  {
    const size_t gof = (size_t)dir * (TCH * 32 * 4096) + npr;
    #pragma unroll
    for (int r = 0; r < 4; r++)
      gxu[r] = gx[gof + (size_t)(mh * 16 + rg * 4 + r) * 4096];
  }

  for (int t = 0; t < TCH; t++){
    const int s = s0 + t;
    const char* img_r = hbuf + (size_t)(grp * 2 + (s & 1)) * 32768;
    char* img_w = hbuf + (size_t)(grp * 2 + ((s + 1) & 1)) * 32768;

    // wait for all 64 producers of this group's image (step t data)
    if (t > 0){
      const unsigned tgt = (unsigned)(bar0 + t);
      const u64* fl = (const u64*)flags;
      while (true){
        u64 v = __hip_atomic_load((u64*)(uintptr_t)(fl + (lane & 31)),
                                  __ATOMIC_RELAXED, __HIP_MEMORY_SCOPE_AGENT);
        bool ok = ((unsigned)v >= tgt) & ((unsigned)(v >> 32) >= tgt);
        if (__all(ok)) break;
        __builtin_amdgcn_s_sleep(1);
      }
      asm volatile("" ::: "memory");   // no staging hoisted above the poll
    }

    // stage 32KB image -> LDS via coherent 16B DMA (8 instr/wave, linear layout)
    {
      const char* src = img_r + wid * 1024 + lane * 16;
      char* dst = smem + wid * 1024;
      #pragma unroll
      for (int i = 0; i < 8; i++)
        g2l16c(src + i * 4096, dst + i * 4096);
    }
    asm volatile("s_waitcnt vmcnt(0)" ::: "memory");
    __syncthreads();

    // gates = h @ Whh_hi^T + h @ Whh_lo^T — two independent MFMA chains
    f32x4 ah = {0.f,0.f,0.f,0.f}, al = {0.f,0.f,0.f,0.f};
    const int abase = c * 2048;
    #pragma unroll
    for (int ks = 0; ks < 32; ks++){
      int b = ks * 64 + rg * 16;
      int addr = abase + (b ^ ((((c & 7) ^ ((b >> 8) & 7))) << 4));
      short8 a = *(const short8*)(smem + addr);
      ah = __builtin_amdgcn_mfma_f32_16x16x32_bf16(a, Bhi[ks], ah, 0, 0, 0);
      al = __builtin_amdgcn_mfma_f32_16x16x32_bf16(a, Blo[ks], al, 0, 0, 0);
    }

    // elementwise LSTM cell (gate exchange via ds_swizzle xor 4/8/12)
    #pragma unroll
    for (int r = 0; r < 4; r++){
      float v = (ah[r] + al[r]) + bf2f(gxu[r]);
      float act = (g == 2) ? tanh_f(v) : sig_f(v);
      float a4  = __int_as_float(__builtin_amdgcn_ds_swizzle(__float_as_int(act), 0x101F));
      float a8  = __int_as_float(__builtin_amdgcn_ds_swizzle(__float_as_int(act), 0x201F));
      float a12 = __int_as_float(__builtin_amdgcn_ds_swizzle(__float_as_int(act), 0x301F));
      float i_s = sel4(act, a4, a8, a12, g);
      float f_s = sel4(act, a4, a8, a12, g ^ 1);
      float g_t = sel4(act, a4, a8, a12, g ^ 2);
      float o_s = sel4(act, a4, a8, a12, g ^ 3);
      float cn = f_s * cst[r] + i_s * g_t;
      cst[r] = cn;
      float hn = o_s * tanh_f(cn);
      if (g == 0){
        int lr = rg * 4 + r;
        tb[lr][wid * 4 + jj] = f2bf(hn);
        if (s == 1023)
          dout[(size_t)dir * 32768 + (size_t)(mh * 16 + lr) * 1024 + u] = hn;
        if (t == TCH - 1)
          cstate[(size_t)dir * 32768 + (size_t)(mh * 16 + lr) * 1024 + u] = cn;
      }
    }
    __syncthreads();   // tb complete; all waves done reading smem

    // h_new -> image: 32 coherent 16B stores (block's 32B per row, swizzled)
    if (tid < 32){
      int lr = tid >> 1, half = tid & 1;
      u32x4 v = *(const u32x4*)&tb[lr][half * 8];
      int bo = ug * 32 + half * 16;
      store16_llc(img_w + img_off(lr, bo), v);
    }

    if (t < TCH - 1){
      // prefetch next step's gx while stores drain
      const size_t gof = (size_t)dir * (TCH * 32 * 4096) + (size_t)(t + 1) * 131072 + npr;
      #pragma unroll
      for (int r = 0; r < 4; r++)
        gxu[r] = gx[gof + (size_t)(mh * 16 + rg * 4 + r) * 4096];

      asm volatile("s_waitcnt vmcnt(0)" ::: "memory");  // drain this wave's h stores
      __syncthreads();                                  // => all waves drained
      if (tid == 0)
        __hip_atomic_store(&flags[ug], bar0 + t + 1,
                           __ATOMIC_RELAXED, __HIP_MEMORY_SCOPE_AGENT);
    }
  }
}

// ---------------- host launcher ----------------
extern "C" void kernel_launch(void* const* d_in, const int* in_sizes, int n_in,
                              void* d_out, int out_size, void* d_ws, size_t ws_size,
                              hipStream_t stream){
  const float* x     = (const float*)d_in[0];
  const float* h0    = (const float*)d_in[1];
  const float* c0    = (const float*)d_in[2];
  const float* Wih_f = (const float*)d_in[3];
  const float* Whh_f = (const float*)d_in[4];
  const float* bih_f = (const float*)d_in[5];
  const float* bhh_f = (const float*)d_in[6];
  const float* Wih_r = (const float*)d_in[7];
  const float* Whh_r = (const float*)d_in[8];
  const float* bih_r = (const float*)d_in[9];
  const float* bhh_r = (const float*)d_in[10];
  float* out = (float*)d_out;

  char* ws = (char*)d_ws;
  u16*   xb    = (u16*)(ws + O_XB);
  u16*   wih   = (u16*)(ws + O_WIH);
  u16*   whhp  = (u16*)(ws + O_WHHP);
  float* bias  = (float*)(ws + O_BIAS);
  char*  hbuf  = (char*)(ws + O_HBUF);
  float* cstw  = (float*)(ws + O_CST);
  int*   cnt   = (int*)(ws + O_CNT);
  u16*   gx    = (u16*)(ws + O_GX);

  // conversions / packing / init (independent)
  k_cvt<<<2048, 256, 0, stream>>>(x, xb, 32 * 1024 * 1024);
  k_cvt<<<512, 256, 0, stream>>>(Wih_f, wih, 4096 * 1024);
  k_cvt<<<512, 256, 0, stream>>>(Wih_r, wih + 4194304, 4096 * 1024);
  k_pack_whh<<<512, 256, 0, stream>>>(Whh_f, Whh_r, whhp);
  k_init<<<64, 256, 0, stream>>>(h0, c0, bih_f, bhh_f, bih_r, bhh_r, hbuf, cstw, bias, cnt);

  // chunked: input-projection GEMM then TCH recurrent steps, 8x
  for (int ch = 0; ch < NCH; ch++){
    k_gemm<<<dim3(32, 32, 2), 256, 0, stream>>>(xb, wih, bias, gx, ch);
    k_rnn<<<dim3(256), dim3(256), 0, stream>>>(gx, whhp, hbuf, cstw, out, cnt,
                                               ch * TCH, ch * (TCH - 1));
  }
}

// Round 6
// 6758.350 us; speedup vs baseline: 2.8876x; 1.1171x over previous
//
#include <hip/hip_runtime.h>
#include <hip/hip_bf16.h>
#include <cstdint>
#include <cstddef>

typedef unsigned short u16;
typedef unsigned long long u64;
typedef __attribute__((ext_vector_type(8))) short short8;
typedef __attribute__((ext_vector_type(4))) float f32x4;
typedef __attribute__((ext_vector_type(4))) unsigned u32x4;

// ---------------- constants ----------------
#define NB 32          // batch
#define NT 1024        // time steps
#define NH 1024        // hidden
#define TCH 128        // time chunk
#define NCH 8          // number of chunks

// workspace offsets (bytes)
#define O_XB   0ull                 // x bf16: 64MB
#define O_WIH  67108864ull          // wih bf16 both dirs: 16MB
#define O_WHHP 83886080ull          // whh packed hi/lo frag-linear: 32MB
#define O_BIAS 117440512ull         // bias sums f32: 32KB
#define O_HBUF 117473280ull         // h images: 4 groups x 2 bufs x 32KB = 256KB
#define O_CST  117735424ull         // c state f32 [dir][b][j]: 256KB
#define O_CNT  117997568ull         // flags: 4 groups x 64 ints (+slack): 4KB
#define O_GX   118001664ull         // Gx bf16: chunk 64MB or full 512MB
#define DSTRIDE_CH   16777216ull    // TCH*32*4096 elems
#define DSTRIDE_FULL 134217728ull   // NT*32*4096 elems
#define WS_NEED_FULL (O_GX + 2ull * DSTRIDE_FULL * 2ull)   // ~625 MB

__device__ __forceinline__ u16 f2bf(float f){
  union { float f; unsigned u; } v; v.f = f;
  unsigned r = v.u + 0x7FFFu + ((v.u >> 16) & 1u);
  return (u16)(r >> 16);
}
__device__ __forceinline__ float bf2f(u16 h){
  union { unsigned u; float f; } v; v.u = ((unsigned)h) << 16;
  return v.f;
}
__device__ __forceinline__ float sig_f(float x){ return 1.0f / (1.0f + __expf(-x)); }
__device__ __forceinline__ float tanh_f(float x){ return 1.0f - 2.0f / (1.0f + __expf(2.0f * x)); }

// plain global->LDS DMA (L2-cached) — used by k_gemm
__device__ __forceinline__ void g2l16(const void* g, void* l){
  __builtin_amdgcn_global_load_lds(
      (const __attribute__((address_space(1))) unsigned int*)g,
      (__attribute__((address_space(3))) unsigned int*)l, 16, 0, 0);
}
// coherent global->LDS DMA: aux = SC0|SC1 -> bypass L0+L2, read at LLC
__device__ __forceinline__ void g2l16c(const void* g, void* l){
  __builtin_amdgcn_global_load_lds(
      (const __attribute__((address_space(1))) unsigned int*)g,
      (__attribute__((address_space(3))) unsigned int*)l, 16, 0, 17);
}
// coherent 16B store (write-through to LLC)
__device__ __forceinline__ void store16_llc(void* p, u32x4 v){
  asm volatile("global_store_dwordx4 %0, %1, off sc0 sc1"
               :: "v"((unsigned long long)(uintptr_t)p), "v"(v) : "memory");
}

__device__ __forceinline__ float sel4(float s0, float s1, float s2, float s3, int k){
  float a = (k & 1) ? s1 : s0;
  float b = (k & 1) ? s3 : s2;
  return (k & 2) ? b : a;
}

// image byte offset for (row lr in 0..15, pre-swizzle byte bo in 0..2047)
__device__ __forceinline__ int img_off(int lr, int bo){
  return lr * 2048 + (bo ^ ((((lr & 7) ^ ((bo >> 8) & 7))) << 4));
}

// ---------------- f32 -> bf16 convert ----------------
__global__ void k_cvt(const float* __restrict__ src, u16* __restrict__ dst, int n){
  int i = (blockIdx.x * blockDim.x + threadIdx.x) * 4;
  int stride = gridDim.x * blockDim.x * 4;
  for (; i < n; i += stride){
    float4 v = *(const float4*)(src + i);
    uint2 p;
    p.x = (unsigned)f2bf(v.x) | ((unsigned)f2bf(v.y) << 16);
    p.y = (unsigned)f2bf(v.z) | ((unsigned)f2bf(v.w) << 16);
    *(uint2*)(dst + i) = p;
  }
}

// ---------------- pack Whh into hi/lo fragment-linear layout ----------------
// frag index = (((dir*128 + jg)*2 + ni)*32 + ks)*2 + part ; 1024B per frag (lane*16B)
// lane c=lane&15 -> weight row n = (c>>2)*1024 + jg*8 + ni*4 + (c&3); k-chunk (lane>>4)*8
__global__ void k_pack_whh(const float* __restrict__ whh_f, const float* __restrict__ whh_r,
                           u16* __restrict__ dst){
  int bx = blockIdx.x;              // 512 blocks: dir*256 + jg*2 + ni
  int dir = bx >> 8, rem = bx & 255;
  int jg = rem >> 1, ni = rem & 1;
  const float* whh = dir ? whh_r : whh_f;
  int tid = threadIdx.x;
  int lane = tid & 63, wq = tid >> 6;
  int c = lane & 15;
  int n = (c >> 2) * 1024 + jg * 8 + ni * 4 + (c & 3);
  int kkb = (lane >> 4) * 8;
  size_t fb = ((((size_t)dir * 128 + jg) * 2 + ni) * 32) * 2;
  for (int q = 0; q < 8; q++){
    int ks = wq * 8 + q;
    const float4* p = (const float4*)(whh + (size_t)n * 1024 + ks * 32 + kkb);
    float4 w0 = p[0], w1 = p[1];
    float w[8] = {w0.x, w0.y, w0.z, w0.w, w1.x, w1.y, w1.z, w1.w};
    unsigned hh[4], ll[4];
    #pragma unroll
    for (int e = 0; e < 4; e++){
      u16 h0 = f2bf(w[2*e]),   l0 = f2bf(w[2*e]   - bf2f(f2bf(w[2*e])));
      u16 h1 = f2bf(w[2*e+1]), l1 = f2bf(w[2*e+1] - bf2f(f2bf(w[2*e+1])));
      hh[e] = (unsigned)h0 | ((unsigned)h1 << 16);
      ll[e] = (unsigned)l0 | ((unsigned)l1 << 16);
    }
    uint4* dh = (uint4*)(dst + (fb + (size_t)ks * 2 + 0) * 512 + lane * 8);
    uint4* dl = (uint4*)(dst + (fb + (size_t)ks * 2 + 1) * 512 + lane * 8);
    *dh = make_uint4(hh[0], hh[1], hh[2], hh[3]);
    *dl = make_uint4(ll[0], ll[1], ll[2], ll[3]);
  }
}

// ---------------- init: bias sums, h0 -> swizzled images, c state, zero flags ----
__global__ void k_init(const float* __restrict__ h0, const float* __restrict__ c0,
                       const float* __restrict__ bih_f, const float* __restrict__ bhh_f,
                       const float* __restrict__ bih_r, const float* __restrict__ bhh_r,
                       char* __restrict__ hbuf, float* __restrict__ cst,
                       float* __restrict__ bias, int* __restrict__ cnt){
  int i = blockIdx.x * blockDim.x + threadIdx.x;
  int stride = gridDim.x * blockDim.x;
  for (int k = i; k < 32768; k += stride){
    int b = k >> 10, j = k & 1023;
    int lr = b & 15, mhb = b >> 4;
    u16 v = f2bf(h0[k]);
    int off = img_off(lr, 2 * j);
    *(u16*)(hbuf + (size_t)((0 * 2 + mhb) * 2) * 32768 + off) = v;  // dir 0
    *(u16*)(hbuf + (size_t)((1 * 2 + mhb) * 2) * 32768 + off) = v;  // dir 1
    float cv = c0[k];
    cst[k] = cv;            // dir0
    cst[32768 + k] = cv;    // dir1
  }
  for (int k = i; k < 8192; k += stride){
    if (k < 4096) bias[k] = bih_f[k] + bhh_f[k];
    else          bias[k] = bih_r[k - 4096] + bhh_r[k - 4096];
  }
  for (int k = i; k < 1024; k += stride) cnt[k] = 0;
}

// ---------------- Phase 1: Gx chunk = x @ Wih^T + bias, store bf16 permuted ----------------
// grid (32, 32, 2): n0 = bx*128 (gate cols), by = batch, bz = dir. 128x128 tile, BK=64.
__global__ __launch_bounds__(256, 2) void k_gemm(const u16* __restrict__ xb,
                                                 const u16* __restrict__ wih,
                                                 const float* __restrict__ bias,
                                                 u16* __restrict__ gx, int chunk,
                                                 int tOff, size_t dirStride){
  __shared__ u16 smem[2 * 16384]; // 2 x 32KB frag-linear, frag f at f*512 u16; A:0..15 B:16..31
  const int tid = threadIdx.x;
  const int lane = tid & 63, wid = tid >> 6;
  const int mi = wid >> 1, ni = wid & 1;
  const int c = lane & 15, rg = lane >> 4;
  const int n0 = blockIdx.x * 128;
  const int bb = blockIdx.y;              // batch
  const int dir = blockIdx.z;
  const u16* wd = wih + (size_t)dir * 4194304;

  f32x4 acc[4][4] = {};

  auto stage = [&](int buf, int k0){
    #pragma unroll
    for (int q = 0; q < 8; q++){
      int f = wid * 8 + q;
      int ks = f & 1;
      int kk = k0 + ks * 32 + rg * 8;
      const u16* src;
      if (f < 16){
        int lr = (f >> 1) * 16 + c;       // local t within chunk
        int tg = dir ? (1023 - chunk * TCH - lr) : (chunk * TCH + lr);
        src = xb + (size_t)(bb * 1024 + tg) * 1024 + kk;
      } else {
        int nt = (f - 16) >> 1;
        src = wd + (size_t)(n0 + nt * 16 + c) * 1024 + kk;
      }
      g2l16((const void*)src, (void*)(smem + buf * 16384 + f * 512));
    }
  };

  stage(0, 0);
  asm volatile("s_waitcnt vmcnt(0)" ::: "memory");
  __syncthreads();

  for (int it = 0; it < 16; it++){
    int cur = it & 1;
    if (it < 15) stage(cur ^ 1, (it + 1) * 64);
    const u16* bp = smem + cur * 16384;
    #pragma unroll
    for (int ks = 0; ks < 2; ks++){
      short8 a[4], b[4];
      #pragma unroll
      for (int im = 0; im < 4; im++)
        a[im] = *(const short8*)(bp + ((mi * 4 + im) * 2 + ks) * 512 + lane * 8);
      #pragma unroll
      for (int in_ = 0; in_ < 4; in_++)
        b[in_] = *(const short8*)(bp + 8192 + ((ni * 4 + in_) * 2 + ks) * 512 + lane * 8);
      #pragma unroll
      for (int im = 0; im < 4; im++)
        #pragma unroll
        for (int in_ = 0; in_ < 4; in_++)
          acc[im][in_] = __builtin_amdgcn_mfma_f32_16x16x32_bf16(a[im], b[in_], acc[im][in_], 0, 0, 0);
    }
    asm volatile("s_waitcnt vmcnt(0)" ::: "memory");
    __syncthreads();
  }

  // epilogue: add bias, permute col, store bf16 at gx[dir][tOff+tl][b][npr]
  u16* gxd = gx + (size_t)dir * dirStride;
  const float* bd = bias + dir * 4096;
  #pragma unroll
  for (int in_ = 0; in_ < 4; in_++){
    int nn = n0 + (ni * 4 + in_) * 16 + c;
    float bv = bd[nn];
    int npr = ((nn & 1023) >> 3) * 32 + ((nn >> 10) << 3) + (nn & 7);
    #pragma unroll
    for (int im = 0; im < 4; im++){
      #pragma unroll
      for (int r = 0; r < 4; r++){
        int tl = (mi * 4 + im) * 16 + rg * 4 + r;   // local t
        gxd[(size_t)((tOff + tl) * 32 + bb) * 4096 + npr] = f2bf(acc[im][in_][r] + bv);
      }
    }
  }
}

// ---------------- Phase 2: recurrent kernel ----------------
// 256 blocks x 256 thr (4 waves), 1 block/CU. bx: dir = bx>>7; mh = (bx>>6)&1; ug = bx&63.
// 4 independent groups (dir,mh) of 64 blocks. Weights AGPR/VGPR-resident (hi+lo).
// h = pre-swizzled 32KB LDS image in hbuf, staged via coherent global_load_lds.
// Release path (wave0 only): 32x16B sc0sc1 stores -> vmcnt(0) -> flag. gx prefetch
// is OFF the release path. Consumers spin-poll 64 flags, then DMA-stage.
__global__ __launch_bounds__(256, 1) void k_rnn(const u16* __restrict__ gx,
                                                const u16* __restrict__ whhp,
                                                char* __restrict__ hbuf,
                                                float* __restrict__ cstate,
                                                float* __restrict__ dout,
                                                int* __restrict__ cnt,
                                                int s0, int bar0, int nsteps,
                                                size_t dirStride){
  __shared__ char smem[32768];                 // h image for (dir,mh): 16 rows x 2048B
  __shared__ __align__(16) u16 tb[16][16];     // h_new transpose buffer [row][unit]
  const int tid = threadIdx.x;
  const int lane = tid & 63, wid = tid >> 6;
  const int bx = blockIdx.x;
  const int dir = bx >> 7, mh = (bx >> 6) & 1, ug = bx & 63;
  const int grp = dir * 2 + mh;
  const int c = lane & 15, rg = lane >> 4;
  const int g = c >> 2, jj = c & 3;
  const int u = ug * 16 + wid * 4 + jj;        // hidden unit for this lane's column
  const int jg = ug * 2 + (wid >> 1), ni = wid & 1;

  // --- Whh fragments into registers (hi + lo) ---
  short8 Bhi[32], Blo[32];
  {
    size_t fb = ((((size_t)dir * 128 + jg) * 2 + ni) * 32) * 2;
    #pragma unroll
    for (int ks = 0; ks < 32; ks++){
      Bhi[ks] = *(const short8*)(whhp + (fb + ks * 2 + 0) * 512 + lane * 8);
      Blo[ks] = *(const short8*)(whhp + (fb + ks * 2 + 1) * 512 + lane * 8);
    }
  }

  // --- c state: rows B = mh*16 + rg*4 + r ---
  float cst[4];
  #pragma unroll
  for (int r = 0; r < 4; r++)
    cst[r] = cstate[(size_t)dir * 32768 + (size_t)(mh * 16 + rg * 4 + r) * 1024 + u];

  const int npr = (u >> 3) * 32 + g * 8 + (u & 7);
  int* flags = cnt + grp * 64;

  // gx prefetch for t=0
  u16 gxu[4];
  {
    const size_t gof = (size_t)dir * dirStride + npr;
    #pragma unroll
    for (int r = 0; r < 4; r++)
      gxu[r] = gx[gof + (size_t)(mh * 16 + rg * 4 + r) * 4096];
  }

  for (int t = 0; t < nsteps; t++){
    const int s = s0 + t;
    const char* img_r = hbuf + (size_t)(grp * 2 + (s & 1)) * 32768;
    char* img_w = hbuf + (size_t)(grp * 2 + ((s + 1) & 1)) * 32768;

    // wait for all 64 producers of this group's image (step t data)
    if (t > 0){
      const unsigned tgt = (unsigned)(bar0 + t);
      const u64* fl = (const u64*)flags;
      while (true){
        u64 v = __hip_atomic_load((u64*)(uintptr_t)(fl + (lane & 31)),
                                  __ATOMIC_RELAXED, __HIP_MEMORY_SCOPE_AGENT);
        bool ok = ((unsigned)v >= tgt) & ((unsigned)(v >> 32) >= tgt);
        if (__all(ok)) break;
      }
      asm volatile("" ::: "memory");   // no staging hoisted above the poll
    }

    // stage 32KB image -> LDS via coherent 16B DMA (8 instr/wave, linear layout)
    {
      const char* src = img_r + wid * 1024 + lane * 16;
      char* dst = smem + wid * 1024;
      #pragma unroll
      for (int i = 0; i < 8; i++)
        g2l16c(src + i * 4096, dst + i * 4096);
    }
    asm volatile("s_waitcnt vmcnt(0)" ::: "memory");
    __syncthreads();

    // gates = h @ Whh_hi^T + h @ Whh_lo^T — two independent MFMA chains
    f32x4 ah = {0.f,0.f,0.f,0.f}, al = {0.f,0.f,0.f,0.f};
    const int abase = c * 2048;
    #pragma unroll
    for (int ks = 0; ks < 32; ks++){
      int b = ks * 64 + rg * 16;
      int addr = abase + (b ^ ((((c & 7) ^ ((b >> 8) & 7))) << 4));
      short8 a = *(const short8*)(smem + addr);
      ah = __builtin_amdgcn_mfma_f32_16x16x32_bf16(a, Bhi[ks], ah, 0, 0, 0);
      al = __builtin_amdgcn_mfma_f32_16x16x32_bf16(a, Blo[ks], al, 0, 0, 0);
    }

    // elementwise LSTM cell (gate exchange via ds_swizzle xor 4/8/12)
    #pragma unroll
    for (int r = 0; r < 4; r++){
      float v = (ah[r] + al[r]) + bf2f(gxu[r]);
      float act = (g == 2) ? tanh_f(v) : sig_f(v);
      float a4  = __int_as_float(__builtin_amdgcn_ds_swizzle(__float_as_int(act), 0x101F));
      float a8  = __int_as_float(__builtin_amdgcn_ds_swizzle(__float_as_int(act), 0x201F));
      float a12 = __int_as_float(__builtin_amdgcn_ds_swizzle(__float_as_int(act), 0x301F));
      float i_s = sel4(act, a4, a8, a12, g);
      float f_s = sel4(act, a4, a8, a12, g ^ 1);
      float g_t = sel4(act, a4, a8, a12, g ^ 2);
      float o_s = sel4(act, a4, a8, a12, g ^ 3);
      float cn = f_s * cst[r] + i_s * g_t;
      cst[r] = cn;
      float hn = o_s * tanh_f(cn);
      if (g == 0){
        int lr = rg * 4 + r;
        tb[lr][wid * 4 + jj] = f2bf(hn);
        if (s == 1023)
          dout[(size_t)dir * 32768 + (size_t)(mh * 16 + lr) * 1024 + u] = hn;
        if (t == nsteps - 1)
          cstate[(size_t)dir * 32768 + (size_t)(mh * 16 + lr) * 1024 + u] = cn;
      }
    }
    __syncthreads();   // tb complete; all waves done reading smem

    // h_new -> image: wave 0 only, 32 coherent 16B stores (swizzled)
    if (tid < 32){
      int lr = tid >> 1, half = tid & 1;
      u32x4 v = *(const u32x4*)&tb[lr][half * 8];
      int bo = ug * 32 + half * 16;
      store16_llc(img_w + img_off(lr, bo), v);
    }

    if (t < nsteps - 1){
      // release path: wave0 drains ITS OWN h stores only, then flags. No block-wide
      // barrier, no gx loads in the drain.
      if (wid == 0){
        asm volatile("s_waitcnt vmcnt(0)" ::: "memory");
        if (tid == 0)
          __hip_atomic_store(&flags[ug], bar0 + t + 1,
                             __ATOMIC_RELAXED, __HIP_MEMORY_SCOPE_AGENT);
      }
      // prefetch next step's gx (waves 1-3 immediately; wave0 after its flag)
      const size_t gof = (size_t)dir * dirStride + (size_t)(t + 1) * 131072 + npr;
      #pragma unroll
      for (int r = 0; r < 4; r++)
        gxu[r] = gx[gof + (size_t)(mh * 16 + rg * 4 + r) * 4096];
    }
  }
}

// ---------------- host launcher ----------------
extern "C" void kernel_launch(void* const* d_in, const int* in_sizes, int n_in,
                              void* d_out, int out_size, void* d_ws, size_t ws_size,
                              hipStream_t stream){
  const float* x     = (const float*)d_in[0];
  const float* h0    = (const float*)d_in[1];
  const float* c0    = (const float*)d_in[2];
  const float* Wih_f = (const float*)d_in[3];
  const float* Whh_f = (const float*)d_in[4];
  const float* bih_f = (const float*)d_in[5];
  const float* bhh_f = (const float*)d_in[6];
  const float* Wih_r = (const float*)d_in[7];
  const float* Whh_r = (const float*)d_in[8];
  const float* bih_r = (const float*)d_in[9];
  const float* bhh_r = (const float*)d_in[10];
  float* out = (float*)d_out;

  char* ws = (char*)d_ws;
  u16*   xb    = (u16*)(ws + O_XB);
  u16*   wih   = (u16*)(ws + O_WIH);
  u16*   whhp  = (u16*)(ws + O_WHHP);
  float* bias  = (float*)(ws + O_BIAS);
  char*  hbuf  = (char*)(ws + O_HBUF);
  float* cstw  = (float*)(ws + O_CST);
  int*   cnt   = (int*)(ws + O_CNT);
  u16*   gx    = (u16*)(ws + O_GX);

  // conversions / packing / init (independent)
  k_cvt<<<2048, 256, 0, stream>>>(x, xb, 32 * 1024 * 1024);
  k_cvt<<<512, 256, 0, stream>>>(Wih_f, wih, 4096 * 1024);
  k_cvt<<<512, 256, 0, stream>>>(Wih_r, wih + 4194304, 4096 * 1024);
  k_pack_whh<<<512, 256, 0, stream>>>(Whh_f, Whh_r, whhp);
  k_init<<<64, 256, 0, stream>>>(h0, c0, bih_f, bhh_f, bih_r, bhh_r, hbuf, cstw, bias, cnt);

  if (ws_size >= WS_NEED_FULL){
    // single-dispatch recurrent path: all 8 gemm chunks into full gx, then one k_rnn
    for (int ch = 0; ch < NCH; ch++)
      k_gemm<<<dim3(32, 32, 2), 256, 0, stream>>>(xb, wih, bias, gx, ch,
                                                  ch * TCH, (size_t)DSTRIDE_FULL);
    k_rnn<<<dim3(256), dim3(256), 0, stream>>>(gx, whhp, hbuf, cstw, out, cnt,
                                               0, 0, NT, (size_t)DSTRIDE_FULL);
  } else {
    // chunked path
    for (int ch = 0; ch < NCH; ch++){
      k_gemm<<<dim3(32, 32, 2), 256, 0, stream>>>(xb, wih, bias, gx, ch,
                                                  0, (size_t)DSTRIDE_CH);
      k_rnn<<<dim3(256), dim3(256), 0, stream>>>(gx, whhp, hbuf, cstw, out, cnt,
                                                 ch * TCH, ch * (TCH - 1), TCH,
                                                 (size_t)DSTRIDE_CH);
    }
  }
}